// Round 7
// baseline (245.101 us; speedup 1.0000x reference)
//
#include <hip/hip_runtime.h>
#include <hip/hip_bf16.h>
#include <math.h>

namespace {
constexpr int Hn  = 16;    // heads
constexpr int DH  = 64;    // head dim
constexpr int S   = 2048;  // seq
constexpr int D   = 1024;  // model dim
constexpr int B   = 2;     // batch
constexpr int N   = B * S; // 4096 rows
}

typedef __attribute__((ext_vector_type(8))) short bf16x8;
typedef __attribute__((ext_vector_type(4))) float f32x4;

#if defined(__has_builtin)
#if __has_builtin(__builtin_amdgcn_exp2f)
#define HAVE_EXP2_BUILTIN 1
#endif
#endif

static __device__ __forceinline__ float exp2_fast(float x) {
#ifdef HAVE_EXP2_BUILTIN
    return __builtin_amdgcn_exp2f(x);
#else
    float r;
    asm("v_exp_f32 %0, %1" : "=v"(r) : "v"(x));
    return r;
#endif
}

// fast bf16 round (half-up) — residual-based hi/lo split keeps fp32 accuracy
static __device__ __forceinline__ ushort bf16rd(float x) {
    unsigned u = __builtin_bit_cast(unsigned, x);
    return (ushort)((u + 0x8000u) >> 16);
}
static __device__ __forceinline__ float bfu2f(ushort h) {
    unsigned u = (unsigned)h << 16;
    return __builtin_bit_cast(float, u);
}
static __device__ __forceinline__ void split1(float a, ushort& h, ushort& l) {
    h = bf16rd(a);
    l = bf16rd(a - bfu2f(h));
}

// ---------------------------------------------------------------------------
// One launch, all input conversions:
//   q,k -> hi/lo bf16;  v -> hi;  Wq,Wk,Wv -> hi;  Wo -> hi/lo.
// ---------------------------------------------------------------------------
__global__ __launch_bounds__(256) void split_all(
    const float4* __restrict__ q, const float4* __restrict__ k, const float4* __restrict__ v,
    const float4* __restrict__ wq, const float4* __restrict__ wk,
    const float4* __restrict__ wv, const float4* __restrict__ wo,
    ushort4* __restrict__ qh, ushort4* __restrict__ ql,
    ushort4* __restrict__ kh, ushort4* __restrict__ kl,
    ushort4* __restrict__ vh,
    ushort4* __restrict__ wqh, ushort4* __restrict__ wkh, ushort4* __restrict__ wvh,
    ushort4* __restrict__ woh, ushort4* __restrict__ wol,
    int n4a, int n4w) {
    const int total = 3 * n4a + 4 * n4w;
    const int stride = gridDim.x * 256;
    for (int i = blockIdx.x * 256 + threadIdx.x; i < total; i += stride) {
        const float4* s;
        ushort4 *ph, *pl;
        int j;
        if (i < 3 * n4a) {
            const int which = i / n4a;
            j = i - which * n4a;
            s  = which == 0 ? q  : which == 1 ? k  : v;
            ph = which == 0 ? qh : which == 1 ? kh : vh;
            pl = which == 0 ? ql : which == 1 ? kl : nullptr;
        } else {
            const int t = i - 3 * n4a;
            const int which = t / n4w;
            j = t - which * n4w;
            s  = which == 0 ? wq  : which == 1 ? wk  : which == 2 ? wv  : wo;
            ph = which == 0 ? wqh : which == 1 ? wkh : which == 2 ? wvh : woh;
            pl = which == 3 ? wol : nullptr;
        }
        const float4 val = s[j];
        if (pl) {
            ushort4 hh, ll;
            split1(val.x, hh.x, ll.x);
            split1(val.y, hh.y, ll.y);
            split1(val.z, hh.z, ll.z);
            split1(val.w, hh.w, ll.w);
            ph[j] = hh;
            pl[j] = ll;
        } else {
            ph[j] = make_ushort4(bf16rd(val.x), bf16rd(val.y), bf16rd(val.z), bf16rd(val.w));
        }
    }
}

// ---------------------------------------------------------------------------
// Merged Q/K/V projection GEMM. Grid 32 x 24; which = blockIdx.y/8:
//   0: Q = 2-pass (q_lo*W + q_hi*W), *qscale, store hi/lo  [B,H,S,DH]
//   1: K = 2-pass, store hi ONLY                           [B,H,S,DH]
//   2: V = 1-pass (v_hi*W), store hi transposed            [B,H,DH,S]
// W used hi-only for all three. Tile 128x128, BK=32, 4 waves (2x2).
// ---------------------------------------------------------------------------
__global__ __launch_bounds__(256) void gemm_qkv(
    const ushort* __restrict__ qsh, const ushort* __restrict__ qsl,
    const ushort* __restrict__ ksh, const ushort* __restrict__ ksl,
    const ushort* __restrict__ vsh,
    const ushort* __restrict__ Wqh, const ushort* __restrict__ Wkh,
    const ushort* __restrict__ Wvh,
    ushort* __restrict__ Qbh, ushort* __restrict__ Qbl,
    ushort* __restrict__ Kbh, ushort* __restrict__ Vtb, float qscale) {
    constexpr int BK = 32;
    constexpr int LDT = 40;
    constexpr int K = D;
    __shared__ __align__(16) ushort sAh[128 * LDT];
    __shared__ __align__(16) ushort sAl[128 * LDT];
    __shared__ __align__(16) ushort sBh[128 * LDT];

    const int tid = threadIdx.x;
    const int which = blockIdx.y >> 3;
    const int m0 = blockIdx.x * 128;
    const int n0 = (blockIdx.y & 7) * 128;

    const ushort* Ah = which == 0 ? qsh : which == 1 ? ksh : vsh;
    const ushort* Al = which == 0 ? qsl : ksl;  // unused for V
    const ushort* Wh = which == 0 ? Wqh : which == 1 ? Wkh : Wvh;
    const bool twop = which < 2;

    const int l   = tid & 63;
    const int wid = tid >> 6;
    const int wm  = wid >> 1;
    const int wn  = wid & 1;
    const int lm  = l & 15;
    const int g   = l >> 4;
    const int lk  = g * 8;

    const int arow0 = tid >> 2;
    const int aslot = (tid & 3) * 8;
    const ushort* gAh0 = Ah + (size_t)(m0 + arow0) * K + aslot;
    const ushort* gAh1 = gAh0 + (size_t)64 * K;
    const ushort* gAl0 = Al + (size_t)(m0 + arow0) * K + aslot;
    const ushort* gAl1 = gAl0 + (size_t)64 * K;
    const ushort* gBh0 = Wh + (size_t)(n0 + arow0) * K + aslot;
    const ushort* gBh1 = gBh0 + (size_t)64 * K;

    const f32x4 fzero = {0.f, 0.f, 0.f, 0.f};
    f32x4 acc[4][4];
#pragma unroll
    for (int mi = 0; mi < 4; ++mi)
#pragma unroll
        for (int ni = 0; ni < 4; ++ni) acc[mi][ni] = fzero;

    uint4 rA0 = *(const uint4*)gAh0, rA1 = *(const uint4*)gAh1;
    uint4 rA2, rA3;
    if (twop) { rA2 = *(const uint4*)gAl0; rA3 = *(const uint4*)gAl1; }
    uint4 rB0 = *(const uint4*)gBh0, rB1 = *(const uint4*)gBh1;

    for (int s = 0; s < K / BK; ++s) {
        __syncthreads();
        *(uint4*)&sAh[arow0 * LDT + aslot]        = rA0;
        *(uint4*)&sAh[(arow0 + 64) * LDT + aslot] = rA1;
        if (twop) {
            *(uint4*)&sAl[arow0 * LDT + aslot]        = rA2;
            *(uint4*)&sAl[(arow0 + 64) * LDT + aslot] = rA3;
        }
        *(uint4*)&sBh[arow0 * LDT + aslot]        = rB0;
        *(uint4*)&sBh[(arow0 + 64) * LDT + aslot] = rB1;
        __syncthreads();

        const int kn = (s + 1) * BK;
        if (kn < K) {
            rA0 = *(const uint4*)(gAh0 + kn); rA1 = *(const uint4*)(gAh1 + kn);
            if (twop) { rA2 = *(const uint4*)(gAl0 + kn); rA3 = *(const uint4*)(gAl1 + kn); }
            rB0 = *(const uint4*)(gBh0 + kn); rB1 = *(const uint4*)(gBh1 + kn);
        }

        bf16x8 ah[4], al[4], bh[4];
#pragma unroll
        for (int mi = 0; mi < 4; ++mi) {
            const int row = wm * 64 + mi * 16 + lm;
            ah[mi] = *(const bf16x8*)&sAh[row * LDT + lk];
            if (twop) al[mi] = *(const bf16x8*)&sAl[row * LDT + lk];
        }
#pragma unroll
        for (int ni = 0; ni < 4; ++ni) {
            const int rowb = wn * 64 + ni * 16 + lm;
            bh[ni] = *(const bf16x8*)&sBh[rowb * LDT + lk];
        }
        __builtin_amdgcn_s_setprio(1);
        if (twop) {
#pragma unroll
            for (int mi = 0; mi < 4; ++mi)
#pragma unroll
                for (int ni = 0; ni < 4; ++ni) {
                    acc[mi][ni] = __builtin_amdgcn_mfma_f32_16x16x32_bf16(
                        al[mi], bh[ni], acc[mi][ni], 0, 0, 0);
                    acc[mi][ni] = __builtin_amdgcn_mfma_f32_16x16x32_bf16(
                        ah[mi], bh[ni], acc[mi][ni], 0, 0, 0);
                }
        } else {
#pragma unroll
            for (int mi = 0; mi < 4; ++mi)
#pragma unroll
                for (int ni = 0; ni < 4; ++ni)
                    acc[mi][ni] = __builtin_amdgcn_mfma_f32_16x16x32_bf16(
                        ah[mi], bh[ni], acc[mi][ni], 0, 0, 0);
        }
        __builtin_amdgcn_s_setprio(0);
    }

#pragma unroll
    for (int mi = 0; mi < 4; ++mi)
#pragma unroll
        for (int ni = 0; ni < 4; ++ni) {
            const int col = n0 + wn * 64 + ni * 16 + lm;
            const int rbase = m0 + wm * 64 + mi * 16 + g * 4;
            const int hh = col >> 6, dh = col & (DH - 1);
            if (which == 0) {  // Q: scaled, hi/lo
#pragma unroll
                for (int r = 0; r < 4; ++r) {
                    const int row = rbase + r;
                    const float val = acc[mi][ni][r] * qscale;
                    const int bb = row >> 11, ss = row & (S - 1);
                    const size_t idx = (((size_t)(bb * Hn + hh)) * S + ss) * DH + dh;
                    ushort hi, lo;
                    split1(val, hi, lo);
                    Qbh[idx] = hi;
                    Qbl[idx] = lo;
                }
            } else if (which == 1) {  // K: hi only
#pragma unroll
                for (int r = 0; r < 4; ++r) {
                    const int row = rbase + r;
                    const int bb = row >> 11, ss = row & (S - 1);
                    const size_t idx = (((size_t)(bb * Hn + hh)) * S + ss) * DH + dh;
                    Kbh[idx] = bf16rd(acc[mi][ni][r]);
                }
            } else {  // V^T: hi only, transposed
                const int bb = rbase >> 11, ss = rbase & (S - 1);
                ushort4 pk;
                pk.x = bf16rd(acc[mi][ni][0]);
                pk.y = bf16rd(acc[mi][ni][1]);
                pk.z = bf16rd(acc[mi][ni][2]);
                pk.w = bf16rd(acc[mi][ni][3]);
                const size_t idx = (((size_t)(bb * Hn + hh)) * DH + dh) * S + ss;
                *(ushort4*)&Vtb[idx] = pk;
            }
        }
}

// ---------------------------------------------------------------------------
// Output projection GEMM (3-pass split-bf16): out = AO * Wo^T, fp32 store.
// Tile 128x64, BK=32, 4 waves (2x2), wave 64x32. 512 blocks = 2/CU.
// ---------------------------------------------------------------------------
__global__ __launch_bounds__(256) void gemm_out(const ushort* __restrict__ Ah,
                                                const ushort* __restrict__ Al,
                                                const ushort* __restrict__ Wh,
                                                const ushort* __restrict__ Wl,
                                                float* __restrict__ C) {
    constexpr int BK = 32;
    constexpr int LDT = 40;
    constexpr int K = D, O = D;
    __shared__ __align__(16) ushort sAh[128 * LDT];
    __shared__ __align__(16) ushort sAl[128 * LDT];
    __shared__ __align__(16) ushort sBh[64 * LDT];
    __shared__ __align__(16) ushort sBl[64 * LDT];

    const int tid = threadIdx.x;
    const int m0 = blockIdx.x * 128;
    const int n0 = blockIdx.y * 64;

    const int l   = tid & 63;
    const int wid = tid >> 6;
    const int wm  = wid >> 1;
    const int wn  = wid & 1;
    const int lm  = l & 15;
    const int g   = l >> 4;
    const int lk  = g * 8;

    const int arow0 = tid >> 2;
    const int aslot = (tid & 3) * 8;
    const ushort* gAh0 = Ah + (size_t)(m0 + arow0) * K + aslot;
    const ushort* gAh1 = gAh0 + (size_t)64 * K;
    const ushort* gAl0 = Al + (size_t)(m0 + arow0) * K + aslot;
    const ushort* gAl1 = gAl0 + (size_t)64 * K;
    const ushort* gBh  = Wh + (size_t)(n0 + arow0) * K + aslot;
    const ushort* gBl  = Wl + (size_t)(n0 + arow0) * K + aslot;

    const f32x4 fzero = {0.f, 0.f, 0.f, 0.f};
    f32x4 acc[4][2];
#pragma unroll
    for (int mi = 0; mi < 4; ++mi)
#pragma unroll
        for (int ni = 0; ni < 2; ++ni) acc[mi][ni] = fzero;

    uint4 rA0 = *(const uint4*)gAh0, rA1 = *(const uint4*)gAh1;
    uint4 rA2 = *(const uint4*)gAl0, rA3 = *(const uint4*)gAl1;
    uint4 rB0 = *(const uint4*)gBh,  rB1 = *(const uint4*)gBl;

    for (int s = 0; s < K / BK; ++s) {
        __syncthreads();
        *(uint4*)&sAh[arow0 * LDT + aslot]        = rA0;
        *(uint4*)&sAh[(arow0 + 64) * LDT + aslot] = rA1;
        *(uint4*)&sAl[arow0 * LDT + aslot]        = rA2;
        *(uint4*)&sAl[(arow0 + 64) * LDT + aslot] = rA3;
        *(uint4*)&sBh[arow0 * LDT + aslot]        = rB0;
        *(uint4*)&sBl[arow0 * LDT + aslot]        = rB1;
        __syncthreads();

        const int kn = (s + 1) * BK;
        if (kn < K) {
            rA0 = *(const uint4*)(gAh0 + kn); rA1 = *(const uint4*)(gAh1 + kn);
            rA2 = *(const uint4*)(gAl0 + kn); rA3 = *(const uint4*)(gAl1 + kn);
            rB0 = *(const uint4*)(gBh + kn);  rB1 = *(const uint4*)(gBl + kn);
        }

        bf16x8 ah[4], al[4], bh[2], bl[2];
#pragma unroll
        for (int mi = 0; mi < 4; ++mi) {
            const int row = wm * 64 + mi * 16 + lm;
            ah[mi] = *(const bf16x8*)&sAh[row * LDT + lk];
            al[mi] = *(const bf16x8*)&sAl[row * LDT + lk];
        }
#pragma unroll
        for (int ni = 0; ni < 2; ++ni) {
            const int rowb = wn * 32 + ni * 16 + lm;
            bh[ni] = *(const bf16x8*)&sBh[rowb * LDT + lk];
            bl[ni] = *(const bf16x8*)&sBl[rowb * LDT + lk];
        }
        __builtin_amdgcn_s_setprio(1);
#pragma unroll
        for (int mi = 0; mi < 4; ++mi)
#pragma unroll
            for (int ni = 0; ni < 2; ++ni) {
                acc[mi][ni] = __builtin_amdgcn_mfma_f32_16x16x32_bf16(
                    al[mi], bh[ni], acc[mi][ni], 0, 0, 0);
                acc[mi][ni] = __builtin_amdgcn_mfma_f32_16x16x32_bf16(
                    ah[mi], bl[ni], acc[mi][ni], 0, 0, 0);
                acc[mi][ni] = __builtin_amdgcn_mfma_f32_16x16x32_bf16(
                    ah[mi], bh[ni], acc[mi][ni], 0, 0, 0);
            }
        __builtin_amdgcn_s_setprio(0);
    }

#pragma unroll
    for (int mi = 0; mi < 4; ++mi)
#pragma unroll
        for (int ni = 0; ni < 2; ++ni) {
            const int col = n0 + wn * 32 + ni * 16 + lm;
            const int rbase = m0 + wm * 64 + mi * 16 + g * 4;
#pragma unroll
            for (int r = 0; r < 4; ++r)
                C[(size_t)(rbase + r) * O + col] = acc[mi][ni][r];
        }
}

// ---------------------------------------------------------------------------
// Barrier-free split-KV MFMA flash attention.
// Block = 128 thr (2 waves) x 32 q rows; each wave owns HALF the KV range
// (no-max softmax => o,l are pure sums; combine via one LDS reduction).
// K/V fragments are loaded DIRECTLY from global (L1/L2-resident; no LDS
// staging, no barriers in the KV loop). P round-trips wave-private LDS.
// ---------------------------------------------------------------------------
__global__ __launch_bounds__(128) void attn_mfma(const ushort* __restrict__ Qbh,
                                                 const ushort* __restrict__ Qbl,
                                                 const ushort* __restrict__ Kbh,
                                                 const ushort* __restrict__ Vt,
                                                 ushort* __restrict__ AOh,
                                                 ushort* __restrict__ AOl) {
    constexpr int LDT = 72;
    __shared__ __align__(16) ushort Ps[64 * LDT];   // 2 waves x 32 q rows
    __shared__ float red[32][68];                   // wave1 -> wave0 o,l

    const int tid = threadIdx.x;
    const int l = tid & 63, w = tid >> 6;
    const int g = l >> 4, l15 = l & 15;
    const int bh = blockIdx.x;
    const int q0 = blockIdx.y * 32;
    const size_t bhb = (size_t)bh * S * DH;

    // Q fragments (pre-scaled by log2e/8 at projection); both waves same q rows
    bf16x8 qh_[2][2], ql_[2][2];
#pragma unroll
    for (int qb = 0; qb < 2; ++qb)
#pragma unroll
        for (int kk = 0; kk < 2; ++kk) {
            const size_t idx = bhb + (size_t)(q0 + qb * 16 + l15) * DH + kk * 32 + g * 8;
            qh_[qb][kk] = *(const bf16x8*)(Qbh + idx);
            ql_[qb][kk] = *(const bf16x8*)(Qbl + idx);
        }

    const f32x4 fzero = {0.f, 0.f, 0.f, 0.f};
    f32x4 o_acc[2][4];
    f32x4 l_acc[2];
#pragma unroll
    for (int qb = 0; qb < 2; ++qb) {
        l_acc[qb] = fzero;
#pragma unroll
        for (int f = 0; f < 4; ++f) o_acc[qb][f] = fzero;
    }

    bf16x8 ones;
#pragma unroll
    for (int i = 0; i < 8; ++i) ones[i] = (short)0x3F80;

    const ushort* Kb = Kbh + bhb;
    const ushort* Vb = Vt + (size_t)bh * DH * S;

    const int kt0 = w * (S / 128);        // wave's half: 16 tiles of 64
    const int kt1 = kt0 + (S / 128);
    for (int kt = kt0; kt < kt1; ++kt) {
        // ---- QK^T 2-pass, K frags direct from global ----
        f32x4 sc[2][4];
#pragma unroll
        for (int qb = 0; qb < 2; ++qb)
#pragma unroll
            for (int f = 0; f < 4; ++f) sc[qb][f] = fzero;
#pragma unroll
        for (int kk = 0; kk < 2; ++kk) {
            bf16x8 kh[4];
#pragma unroll
            for (int f = 0; f < 4; ++f)
                kh[f] = *(const bf16x8*)(Kb + (size_t)(kt * 64 + f * 16 + l15) * DH + kk * 32 + g * 8);
            __builtin_amdgcn_s_setprio(1);
#pragma unroll
            for (int f = 0; f < 4; ++f)
#pragma unroll
                for (int qb = 0; qb < 2; ++qb) {
                    sc[qb][f] = __builtin_amdgcn_mfma_f32_16x16x32_bf16(
                        ql_[qb][kk], kh[f], sc[qb][f], 0, 0, 0);
                    sc[qb][f] = __builtin_amdgcn_mfma_f32_16x16x32_bf16(
                        qh_[qb][kk], kh[f], sc[qb][f], 0, 0, 0);
                }
            __builtin_amdgcn_s_setprio(0);
        }

        // ---- P = exp2(sc) -> wave-private LDS (chunk-XOR swizzled) ----
#pragma unroll
        for (int qb = 0; qb < 2; ++qb)
#pragma unroll
            for (int f = 0; f < 4; ++f) {
#pragma unroll
                for (int r = 0; r < 4; ++r) {
                    const int prow = w * 32 + qb * 16 + g * 4 + r;
                    const int chunk = (f * 2 + (l15 >> 3)) ^ ((prow >> 2) & 7);
                    Ps[prow * LDT + chunk * 8 + (l15 & 7)] =
                        bf16rd(exp2_fast(sc[qb][f][r]));
                }
            }

        // ---- PV + row-sum; V frags direct from global ----
#pragma unroll
        for (int kk = 0; kk < 2; ++kk) {
            bf16x8 vt[4];
#pragma unroll
            for (int f = 0; f < 4; ++f)
                vt[f] = *(const bf16x8*)(Vb + (size_t)(f * 16 + l15) * S + kt * 64 + kk * 32 + g * 8);
            const int row0 = w * 32 + l15;
            const int row1 = row0 + 16;
            const int ck = kk * 4 + g;
            const bf16x8 pa0 = *(const bf16x8*)&Ps[row0 * LDT + ((ck ^ ((row0 >> 2) & 7)) * 8)];
            const bf16x8 pa1 = *(const bf16x8*)&Ps[row1 * LDT + ((ck ^ ((row1 >> 2) & 7)) * 8)];
            __builtin_amdgcn_s_setprio(1);
            l_acc[0] = __builtin_amdgcn_mfma_f32_16x16x32_bf16(pa0, ones, l_acc[0], 0, 0, 0);
            l_acc[1] = __builtin_amdgcn_mfma_f32_16x16x32_bf16(pa1, ones, l_acc[1], 0, 0, 0);
#pragma unroll
            for (int f = 0; f < 4; ++f) {
                o_acc[0][f] = __builtin_amdgcn_mfma_f32_16x16x32_bf16(pa0, vt[f], o_acc[0][f], 0, 0, 0);
                o_acc[1][f] = __builtin_amdgcn_mfma_f32_16x16x32_bf16(pa1, vt[f], o_acc[1][f], 0, 0, 0);
            }
            __builtin_amdgcn_s_setprio(0);
        }
    }

    // ---- combine the two waves' partial sums via LDS ----
    if (w == 1) {
#pragma unroll
        for (int qb = 0; qb < 2; ++qb)
#pragma unroll
            for (int r = 0; r < 4; ++r) {
                const int row = qb * 16 + g * 4 + r;
#pragma unroll
                for (int f = 0; f < 4; ++f)
                    red[row][f * 16 + l15] = o_acc[qb][f][r];
                if (l15 == 0) red[row][64] = l_acc[qb][r];
            }
    }
    __syncthreads();
    if (w == 0) {
        const int bb = bh >> 4, hh = bh & 15;
#pragma unroll
        for (int qb = 0; qb < 2; ++qb)
#pragma unroll
            for (int r = 0; r < 4; ++r) {
                const int row = qb * 16 + g * 4 + r;
                const float lsum = l_acc[qb][r] + red[row][64];
                const float inv = 1.f / lsum;
                const int srow = q0 + row;
#pragma unroll
                for (int f = 0; f < 4; ++f) {
                    const float val = (o_acc[qb][f][r] + red[row][f * 16 + l15]) * inv;
                    const size_t idx = ((size_t)(bb * S + srow)) * D + hh * DH + f * 16 + l15;
                    ushort hi, lo;
                    split1(val, hi, lo);
                    AOh[idx] = hi;
                    AOl[idx] = lo;
                }
            }
    }
}

extern "C" void kernel_launch(void* const* d_in, const int* in_sizes, int n_in,
                              void* d_out, int out_size, void* d_ws, size_t ws_size,
                              hipStream_t stream) {
    (void)in_sizes; (void)n_in; (void)out_size; (void)ws_size;
    const float* q  = (const float*)d_in[0];
    const float* k  = (const float*)d_in[1];
    const float* v  = (const float*)d_in[2];
    const float* Wq = (const float*)d_in[3];
    const float* Wk = (const float*)d_in[4];
    const float* Wv = (const float*)d_in[5];
    const float* Wo = (const float*)d_in[6];
    float* out = (float*)d_out;

    uint8_t* w8 = (uint8_t*)d_ws;
    constexpr size_t MB = 1u << 20;
    ushort* qsh = (ushort*)(w8 + 0 * MB);
    ushort* qsl = (ushort*)(w8 + 8 * MB);
    ushort* ksh = (ushort*)(w8 + 16 * MB);
    ushort* ksl = (ushort*)(w8 + 24 * MB);
    ushort* vsh = (ushort*)(w8 + 32 * MB);
    // weight splits (hi for all, lo only for Wo): [40, 50 MB)
    ushort* Wqh = (ushort*)(w8 + 40 * MB);
    ushort* Wkh = (ushort*)(w8 + 42 * MB);
    ushort* Wvh = (ushort*)(w8 + 44 * MB);
    ushort* Woh = (ushort*)(w8 + 46 * MB);
    ushort* Wol = (ushort*)(w8 + 48 * MB);
    // projected bf16 tensors: [56, 88 MB)
    ushort* Qbh = (ushort*)(w8 + 56 * MB);
    ushort* Qbl = (ushort*)(w8 + 64 * MB);
    ushort* Kbh = (ushort*)(w8 + 72 * MB);
    ushort* Vtb = (ushort*)(w8 + 80 * MB);
    // attention output hi/lo: reuse dead q-split region
    ushort* AOh = (ushort*)(w8 + 0 * MB);
    ushort* AOl = (ushort*)(w8 + 8 * MB);

    const int n4_act = (N * D) / 4;
    const int n4_w   = (D * D) / 4;
    const dim3 blk(256);

    split_all<<<2048, blk, 0, stream>>>(
        (const float4*)q, (const float4*)k, (const float4*)v,
        (const float4*)Wq, (const float4*)Wk, (const float4*)Wv, (const float4*)Wo,
        (ushort4*)qsh, (ushort4*)qsl, (ushort4*)ksh, (ushort4*)ksl,
        (ushort4*)vsh,
        (ushort4*)Wqh, (ushort4*)Wkh, (ushort4*)Wvh,
        (ushort4*)Woh, (ushort4*)Wol,
        n4_act, n4_w);

    const float qscale = 0.125f * 1.4426950408889634f;
    gemm_qkv<<<dim3(N / 128, 24), blk, 0, stream>>>(
        qsh, qsl, ksh, ksl, vsh,
        Wqh, Wkh, Wvh,
        Qbh, Qbl, Kbh, Vtb, qscale);

    attn_mfma<<<dim3(B * Hn, S / 32), dim3(128), 0, stream>>>(
        Qbh, Qbl, Kbh, Vtb, AOh, AOl);

    gemm_out<<<dim3(N / 128, D / 64), blk, 0, stream>>>(AOh, AOl, Woh, Wol, out);
}

// Round 8
// 146.902 us; speedup vs baseline: 1.6685x; 1.6685x over previous
//
#include <hip/hip_runtime.h>
#include <hip/hip_bf16.h>
#include <math.h>

namespace {
constexpr int Hn  = 16;    // heads
constexpr int DH  = 64;    // head dim
constexpr int S   = 2048;  // seq
constexpr int D   = 1024;  // model dim
constexpr int B   = 2;     // batch
constexpr int N   = B * S; // 4096 rows
}

typedef __attribute__((ext_vector_type(8))) short bf16x8;
typedef __attribute__((ext_vector_type(4))) float f32x4;

#if defined(__has_builtin)
#if __has_builtin(__builtin_amdgcn_exp2f)
#define HAVE_EXP2_BUILTIN 1
#endif
#endif

static __device__ __forceinline__ float exp2_fast(float x) {
#ifdef HAVE_EXP2_BUILTIN
    return __builtin_amdgcn_exp2f(x);
#else
    float r;
    asm("v_exp_f32 %0, %1" : "=v"(r) : "v"(x));
    return r;
#endif
}

// fast bf16 round (half-up); residual split keeps fp32 accuracy where used
static __device__ __forceinline__ ushort bf16rd(float x) {
    unsigned u = __builtin_bit_cast(unsigned, x);
    return (ushort)((u + 0x8000u) >> 16);
}
static __device__ __forceinline__ float bfu2f(ushort h) {
    unsigned u = (unsigned)h << 16;
    return __builtin_bit_cast(float, u);
}
static __device__ __forceinline__ void split1(float a, ushort& h, ushort& l) {
    h = bf16rd(a);
    l = bf16rd(a - bfu2f(h));
}
// pack 2 fp32 -> u32 holding 2 bf16 (lo in low half)
static __device__ __forceinline__ unsigned pk2bf(float lo, float hi) {
    unsigned a = (__builtin_bit_cast(unsigned, lo) + 0x8000u) >> 16;
    unsigned b = (__builtin_bit_cast(unsigned, hi) + 0x8000u) & 0xFFFF0000u;
    return a | b;
}
static __device__ __forceinline__ uint4 pkrow(float4 x, float4 y) {
    uint4 r;
    r.x = pk2bf(x.x, x.y); r.y = pk2bf(x.z, x.w);
    r.z = pk2bf(y.x, y.y); r.w = pk2bf(y.z, y.w);
    return r;
}

// ---------------------------------------------------------------------------
// Weights-only split: Wq,Wk,Wv -> hi;  Wo -> hi/lo.
// ---------------------------------------------------------------------------
__global__ __launch_bounds__(256) void split_w(
    const float4* __restrict__ wq, const float4* __restrict__ wk,
    const float4* __restrict__ wv, const float4* __restrict__ wo,
    ushort4* __restrict__ wqh, ushort4* __restrict__ wkh, ushort4* __restrict__ wvh,
    ushort4* __restrict__ woh, ushort4* __restrict__ wol, int n4w) {
    const int total = 4 * n4w;
    const int stride = gridDim.x * 256;
    for (int i = blockIdx.x * 256 + threadIdx.x; i < total; i += stride) {
        const int which = i / n4w;
        const int j = i - which * n4w;
        const float4* s = which == 0 ? wq : which == 1 ? wk : which == 2 ? wv : wo;
        const float4 val = s[j];
        if (which == 3) {
            ushort4 hh, ll;
            split1(val.x, hh.x, ll.x);
            split1(val.y, hh.y, ll.y);
            split1(val.z, hh.z, ll.z);
            split1(val.w, hh.w, ll.w);
            woh[j] = hh;
            wol[j] = ll;
        } else {
            ushort4* ph = which == 0 ? wqh : which == 1 ? wkh : wvh;
            ph[j] = make_ushort4(bf16rd(val.x), bf16rd(val.y), bf16rd(val.z), bf16rd(val.w));
        }
    }
}

// ---------------------------------------------------------------------------
// Merged Q/K/V projection, 1-pass bf16 each, fp32 A converted in-register.
// Grid 32 x 24; which = blockIdx.y/8: 0->Q (scaled, [B,H,S,DH]),
// 1->K ([B,H,S,DH]), 2->V^T ([B,H,DH,S]). All outputs bf16 hi only.
// Tile 128x128, BK=32, 4 waves (2x2). Double-buffered LDS, ONE barrier/tile.
// ---------------------------------------------------------------------------
__global__ __launch_bounds__(256) void gemm_qkv(
    const float* __restrict__ qf, const float* __restrict__ kf,
    const float* __restrict__ vf,
    const ushort* __restrict__ Wqh, const ushort* __restrict__ Wkh,
    const ushort* __restrict__ Wvh,
    ushort* __restrict__ Qbh, ushort* __restrict__ Kbh,
    ushort* __restrict__ Vtb, float qscale) {
    constexpr int BK = 32;
    constexpr int LDT = 40;
    constexpr int K = D;
    __shared__ __align__(16) ushort sA[2][128 * LDT];
    __shared__ __align__(16) ushort sB[2][128 * LDT];

    const int tid = threadIdx.x;
    const int which = blockIdx.y >> 3;
    const int m0 = blockIdx.x * 128;
    const int n0 = (blockIdx.y & 7) * 128;

    const float*  A  = which == 0 ? qf : which == 1 ? kf : vf;
    const ushort* Wh = which == 0 ? Wqh : which == 1 ? Wkh : Wvh;

    const int l   = tid & 63;
    const int wid = tid >> 6;
    const int wm  = wid >> 1;
    const int wn  = wid & 1;
    const int lm  = l & 15;
    const int g   = l >> 4;
    const int lk  = g * 8;

    const int arow0 = tid >> 2;       // 0..63 (rows r and r+64 per thread)
    const int aslot = (tid & 3) * 8;  // element offset in K dim
    const float*  gA0 = A + (size_t)(m0 + arow0) * K + aslot;
    const float*  gA1 = gA0 + (size_t)64 * K;
    const ushort* gB0 = Wh + (size_t)(n0 + arow0) * K + aslot;
    const ushort* gB1 = gB0 + (size_t)64 * K;

    const f32x4 fzero = {0.f, 0.f, 0.f, 0.f};
    f32x4 acc[4][4];
#pragma unroll
    for (int mi = 0; mi < 4; ++mi)
#pragma unroll
        for (int ni = 0; ni < 4; ++ni) acc[mi][ni] = fzero;

    // tile 0 loads
    float4 a00 = *(const float4*)gA0, a01 = *(const float4*)(gA0 + 4);
    float4 a10 = *(const float4*)gA1, a11 = *(const float4*)(gA1 + 4);
    uint4  b0  = *(const uint4*)gB0,  b1  = *(const uint4*)gB1;

    // prologue: write buf0, issue tile-1 loads, one barrier
    *(uint4*)&sA[0][arow0 * LDT + aslot]        = pkrow(a00, a01);
    *(uint4*)&sA[0][(arow0 + 64) * LDT + aslot] = pkrow(a10, a11);
    *(uint4*)&sB[0][arow0 * LDT + aslot]        = b0;
    *(uint4*)&sB[0][(arow0 + 64) * LDT + aslot] = b1;
    a00 = *(const float4*)(gA0 + BK); a01 = *(const float4*)(gA0 + BK + 4);
    a10 = *(const float4*)(gA1 + BK); a11 = *(const float4*)(gA1 + BK + 4);
    b0  = *(const uint4*)(gB0 + BK);  b1  = *(const uint4*)(gB1 + BK);
    __syncthreads();

    constexpr int NS = K / BK;  // 32
    int cur = 0;
    for (int s = 0; s < NS; ++s) {
        bf16x8 ah[4], bh[4];
#pragma unroll
        for (int mi = 0; mi < 4; ++mi)
            ah[mi] = *(const bf16x8*)&sA[cur][(wm * 64 + mi * 16 + lm) * LDT + lk];
#pragma unroll
        for (int ni = 0; ni < 4; ++ni)
            bh[ni] = *(const bf16x8*)&sB[cur][(wn * 64 + ni * 16 + lm) * LDT + lk];
        __builtin_amdgcn_s_setprio(1);
#pragma unroll
        for (int mi = 0; mi < 4; ++mi)
#pragma unroll
            for (int ni = 0; ni < 4; ++ni)
                acc[mi][ni] = __builtin_amdgcn_mfma_f32_16x16x32_bf16(
                    ah[mi], bh[ni], acc[mi][ni], 0, 0, 0);
        __builtin_amdgcn_s_setprio(0);

        if (s < NS - 1) {
            const int nx = cur ^ 1;
            *(uint4*)&sA[nx][arow0 * LDT + aslot]        = pkrow(a00, a01);
            *(uint4*)&sA[nx][(arow0 + 64) * LDT + aslot] = pkrow(a10, a11);
            *(uint4*)&sB[nx][arow0 * LDT + aslot]        = b0;
            *(uint4*)&sB[nx][(arow0 + 64) * LDT + aslot] = b1;
            if (s < NS - 2) {
                const int kn = (s + 2) * BK;
                a00 = *(const float4*)(gA0 + kn); a01 = *(const float4*)(gA0 + kn + 4);
                a10 = *(const float4*)(gA1 + kn); a11 = *(const float4*)(gA1 + kn + 4);
                b0  = *(const uint4*)(gB0 + kn);  b1  = *(const uint4*)(gB1 + kn);
            }
            __syncthreads();
            cur = nx;
        }
    }

#pragma unroll
    for (int mi = 0; mi < 4; ++mi)
#pragma unroll
        for (int ni = 0; ni < 4; ++ni) {
            const int col = n0 + wn * 64 + ni * 16 + lm;
            const int rbase = m0 + wm * 64 + mi * 16 + g * 4;
            const int hh = col >> 6, dh = col & (DH - 1);
            if (which == 0) {  // Q: scaled, hi
#pragma unroll
                for (int r = 0; r < 4; ++r) {
                    const int row = rbase + r;
                    const int bb = row >> 11, ss = row & (S - 1);
                    const size_t idx = (((size_t)(bb * Hn + hh)) * S + ss) * DH + dh;
                    Qbh[idx] = bf16rd(acc[mi][ni][r] * qscale);
                }
            } else if (which == 1) {  // K: hi
#pragma unroll
                for (int r = 0; r < 4; ++r) {
                    const int row = rbase + r;
                    const int bb = row >> 11, ss = row & (S - 1);
                    const size_t idx = (((size_t)(bb * Hn + hh)) * S + ss) * DH + dh;
                    Kbh[idx] = bf16rd(acc[mi][ni][r]);
                }
            } else {  // V^T: hi, transposed
                const int bb = rbase >> 11, ss = rbase & (S - 1);
                ushort4 pk;
                pk.x = bf16rd(acc[mi][ni][0]);
                pk.y = bf16rd(acc[mi][ni][1]);
                pk.z = bf16rd(acc[mi][ni][2]);
                pk.w = bf16rd(acc[mi][ni][3]);
                const size_t idx = (((size_t)(bb * Hn + hh)) * DH + dh) * S + ss;
                *(ushort4*)&Vtb[idx] = pk;
            }
        }
}

// ---------------------------------------------------------------------------
// Output projection GEMM (3-pass split-bf16): out = AO * Wo^T, fp32 store.
// Tile 128x64, BK=32, 4 waves (2x2). Double-buffered LDS, ONE barrier/tile.
// ---------------------------------------------------------------------------
__global__ __launch_bounds__(256) void gemm_out(const ushort* __restrict__ Ah,
                                                const ushort* __restrict__ Al,
                                                const ushort* __restrict__ Wh,
                                                const ushort* __restrict__ Wl,
                                                float* __restrict__ C) {
    constexpr int BK = 32;
    constexpr int LDT = 40;
    constexpr int K = D, O = D;
    __shared__ __align__(16) ushort sAh[2][128 * LDT];
    __shared__ __align__(16) ushort sAl[2][128 * LDT];
    __shared__ __align__(16) ushort sBh[2][64 * LDT];
    __shared__ __align__(16) ushort sBl[2][64 * LDT];

    const int tid = threadIdx.x;
    const int m0 = blockIdx.x * 128;
    const int n0 = blockIdx.y * 64;

    const int l   = tid & 63;
    const int wid = tid >> 6;
    const int wm  = wid >> 1;
    const int wn  = wid & 1;
    const int lm  = l & 15;
    const int g   = l >> 4;
    const int lk  = g * 8;

    const int arow0 = tid >> 2;
    const int aslot = (tid & 3) * 8;
    const ushort* gAh0 = Ah + (size_t)(m0 + arow0) * K + aslot;
    const ushort* gAh1 = gAh0 + (size_t)64 * K;
    const ushort* gAl0 = Al + (size_t)(m0 + arow0) * K + aslot;
    const ushort* gAl1 = gAl0 + (size_t)64 * K;
    const ushort* gBh  = Wh + (size_t)(n0 + arow0) * K + aslot;
    const ushort* gBl  = Wl + (size_t)(n0 + arow0) * K + aslot;

    const f32x4 fzero = {0.f, 0.f, 0.f, 0.f};
    f32x4 acc[4][2];
#pragma unroll
    for (int mi = 0; mi < 4; ++mi)
#pragma unroll
        for (int ni = 0; ni < 2; ++ni) acc[mi][ni] = fzero;

    uint4 rA0 = *(const uint4*)gAh0, rA1 = *(const uint4*)gAh1;
    uint4 rA2 = *(const uint4*)gAl0, rA3 = *(const uint4*)gAl1;
    uint4 rB0 = *(const uint4*)gBh,  rB1 = *(const uint4*)gBl;

    *(uint4*)&sAh[0][arow0 * LDT + aslot]        = rA0;
    *(uint4*)&sAh[0][(arow0 + 64) * LDT + aslot] = rA1;
    *(uint4*)&sAl[0][arow0 * LDT + aslot]        = rA2;
    *(uint4*)&sAl[0][(arow0 + 64) * LDT + aslot] = rA3;
    *(uint4*)&sBh[0][arow0 * LDT + aslot]        = rB0;
    *(uint4*)&sBl[0][arow0 * LDT + aslot]        = rB1;
    rA0 = *(const uint4*)(gAh0 + BK); rA1 = *(const uint4*)(gAh1 + BK);
    rA2 = *(const uint4*)(gAl0 + BK); rA3 = *(const uint4*)(gAl1 + BK);
    rB0 = *(const uint4*)(gBh + BK);  rB1 = *(const uint4*)(gBl + BK);
    __syncthreads();

    constexpr int NS = K / BK;
    int cur = 0;
    for (int s = 0; s < NS; ++s) {
        bf16x8 ah[4], al[4], bh[2], bl[2];
#pragma unroll
        for (int mi = 0; mi < 4; ++mi) {
            const int row = wm * 64 + mi * 16 + lm;
            ah[mi] = *(const bf16x8*)&sAh[cur][row * LDT + lk];
            al[mi] = *(const bf16x8*)&sAl[cur][row * LDT + lk];
        }
#pragma unroll
        for (int ni = 0; ni < 2; ++ni) {
            const int rowb = wn * 32 + ni * 16 + lm;
            bh[ni] = *(const bf16x8*)&sBh[cur][rowb * LDT + lk];
            bl[ni] = *(const bf16x8*)&sBl[cur][rowb * LDT + lk];
        }
        __builtin_amdgcn_s_setprio(1);
#pragma unroll
        for (int mi = 0; mi < 4; ++mi)
#pragma unroll
            for (int ni = 0; ni < 2; ++ni) {
                acc[mi][ni] = __builtin_amdgcn_mfma_f32_16x16x32_bf16(
                    al[mi], bh[ni], acc[mi][ni], 0, 0, 0);
                acc[mi][ni] = __builtin_amdgcn_mfma_f32_16x16x32_bf16(
                    ah[mi], bl[ni], acc[mi][ni], 0, 0, 0);
                acc[mi][ni] = __builtin_amdgcn_mfma_f32_16x16x32_bf16(
                    ah[mi], bh[ni], acc[mi][ni], 0, 0, 0);
            }
        __builtin_amdgcn_s_setprio(0);

        if (s < NS - 1) {
            const int nx = cur ^ 1;
            *(uint4*)&sAh[nx][arow0 * LDT + aslot]        = rA0;
            *(uint4*)&sAh[nx][(arow0 + 64) * LDT + aslot] = rA1;
            *(uint4*)&sAl[nx][arow0 * LDT + aslot]        = rA2;
            *(uint4*)&sAl[nx][(arow0 + 64) * LDT + aslot] = rA3;
            *(uint4*)&sBh[nx][arow0 * LDT + aslot]        = rB0;
            *(uint4*)&sBl[nx][arow0 * LDT + aslot]        = rB1;
            if (s < NS - 2) {
                const int kn = (s + 2) * BK;
                rA0 = *(const uint4*)(gAh0 + kn); rA1 = *(const uint4*)(gAh1 + kn);
                rA2 = *(const uint4*)(gAl0 + kn); rA3 = *(const uint4*)(gAl1 + kn);
                rB0 = *(const uint4*)(gBh + kn);  rB1 = *(const uint4*)(gBl + kn);
            }
            __syncthreads();
            cur = nx;
        }
    }

#pragma unroll
    for (int mi = 0; mi < 4; ++mi)
#pragma unroll
        for (int ni = 0; ni < 2; ++ni) {
            const int col = n0 + wn * 32 + ni * 16 + lm;
            const int rbase = m0 + wm * 64 + mi * 16 + g * 4;
#pragma unroll
            for (int r = 0; r < 4; ++r)
                C[(size_t)(rbase + r) * O + col] = acc[mi][ni][r];
        }
}

// ---------------------------------------------------------------------------
// MFMA flash attention, no-max softmax, QK^T 1-pass (Q,K plain bf16; log2e/8
// folded into Q). Row-sum via MFMA vs ones. Block = 4 waves x 128 q rows;
// KV tiles of 64, double-buffered LDS with ONE barrier per tile.
// ---------------------------------------------------------------------------
__global__ __launch_bounds__(256) void attn_mfma(const ushort* __restrict__ Qbh,
                                                 const ushort* __restrict__ Kbh,
                                                 const ushort* __restrict__ Vt,
                                                 ushort* __restrict__ AOh,
                                                 ushort* __restrict__ AOl) {
    constexpr int LDT = 72;
    __shared__ __align__(16) ushort Ksh[2][64 * LDT];
    __shared__ __align__(16) ushort Vts[2][64 * LDT];
    __shared__ __align__(16) ushort Ps[128 * LDT];

    const int tid = threadIdx.x;
    const int l = tid & 63, w = tid >> 6;
    const int g = l >> 4, l15 = l & 15;
    const int bh = blockIdx.x;
    const int q0 = blockIdx.y * 128;
    const size_t bhb = (size_t)bh * S * DH;

    bf16x8 qh_[2][2];
#pragma unroll
    for (int qb = 0; qb < 2; ++qb)
#pragma unroll
        for (int kk = 0; kk < 2; ++kk) {
            const size_t idx = bhb + (size_t)(q0 + w * 32 + qb * 16 + l15) * DH + kk * 32 + g * 8;
            qh_[qb][kk] = *(const bf16x8*)(Qbh + idx);
        }

    const int r_st = tid >> 2;
    const int c0 = (tid & 3) * 16;
    const ushort* gKh = Kbh + bhb + (size_t)r_st * DH + c0;
    const ushort* gVt = Vt + (size_t)bh * DH * S + (size_t)r_st * S + c0;

    uint4 pk0 = *(const uint4*)gKh, pk1 = *(const uint4*)(gKh + 8);
    uint4 pv0 = *(const uint4*)gVt, pv1 = *(const uint4*)(gVt + 8);

    const f32x4 fzero = {0.f, 0.f, 0.f, 0.f};
    f32x4 o_acc[2][4];
    f32x4 l_acc[2];
#pragma unroll
    for (int qb = 0; qb < 2; ++qb) {
        l_acc[qb] = fzero;
#pragma unroll
        for (int f = 0; f < 4; ++f) o_acc[qb][f] = fzero;
    }

    bf16x8 ones;
#pragma unroll
    for (int i = 0; i < 8; ++i) ones[i] = (short)0x3F80;

    // prologue: write buf0, issue tile-1 loads, one barrier
    *(uint4*)&Ksh[0][r_st * LDT + c0]     = pk0;
    *(uint4*)&Ksh[0][r_st * LDT + c0 + 8] = pk1;
    *(uint4*)&Vts[0][r_st * LDT + c0]     = pv0;
    *(uint4*)&Vts[0][r_st * LDT + c0 + 8] = pv1;
    pk0 = *(const uint4*)(gKh + 64 * DH); pk1 = *(const uint4*)(gKh + 64 * DH + 8);
    pv0 = *(const uint4*)(gVt + 64);      pv1 = *(const uint4*)(gVt + 64 + 8);
    __syncthreads();

    constexpr int NT = S / 64;  // 32
    int cur = 0;
    for (int kt = 0; kt < NT; ++kt) {
        // ---- QK^T 1-pass ----
        f32x4 sc[2][4];
#pragma unroll
        for (int qb = 0; qb < 2; ++qb)
#pragma unroll
            for (int f = 0; f < 4; ++f) sc[qb][f] = fzero;
#pragma unroll
        for (int kk = 0; kk < 2; ++kk) {
            bf16x8 kh[4];
#pragma unroll
            for (int f = 0; f < 4; ++f)
                kh[f] = *(const bf16x8*)&Ksh[cur][(f * 16 + l15) * LDT + kk * 32 + g * 8];
            __builtin_amdgcn_s_setprio(1);
#pragma unroll
            for (int f = 0; f < 4; ++f)
#pragma unroll
                for (int qb = 0; qb < 2; ++qb)
                    sc[qb][f] = __builtin_amdgcn_mfma_f32_16x16x32_bf16(
                        qh_[qb][kk], kh[f], sc[qb][f], 0, 0, 0);
            __builtin_amdgcn_s_setprio(0);
        }

        // ---- P = exp2(sc) -> LDS (chunk-XOR swizzled, wave-private) ----
#pragma unroll
        for (int qb = 0; qb < 2; ++qb)
#pragma unroll
            for (int f = 0; f < 4; ++f) {
#pragma unroll
                for (int r = 0; r < 4; ++r) {
                    const int prow = w * 32 + qb * 16 + g * 4 + r;
                    const int chunk = (f * 2 + (l15 >> 3)) ^ ((prow >> 2) & 7);
                    Ps[prow * LDT + chunk * 8 + (l15 & 7)] =
                        bf16rd(exp2_fast(sc[qb][f][r]));
                }
            }

        // ---- PV + row-sum ----
#pragma unroll
        for (int kk = 0; kk < 2; ++kk) {
            const int row0 = w * 32 + l15;
            const int row1 = row0 + 16;
            const int ck = kk * 4 + g;
            const bf16x8 pa0 = *(const bf16x8*)&Ps[row0 * LDT + ((ck ^ ((row0 >> 2) & 7)) * 8)];
            const bf16x8 pa1 = *(const bf16x8*)&Ps[row1 * LDT + ((ck ^ ((row1 >> 2) & 7)) * 8)];
            __builtin_amdgcn_s_setprio(1);
            l_acc[0] = __builtin_amdgcn_mfma_f32_16x16x32_bf16(pa0, ones, l_acc[0], 0, 0, 0);
            l_acc[1] = __builtin_amdgcn_mfma_f32_16x16x32_bf16(pa1, ones, l_acc[1], 0, 0, 0);
#pragma unroll
            for (int f = 0; f < 4; ++f) {
                const bf16x8 vt = *(const bf16x8*)&Vts[cur][(f * 16 + l15) * LDT + kk * 32 + g * 8];
                o_acc[0][f] = __builtin_amdgcn_mfma_f32_16x16x32_bf16(pa0, vt, o_acc[0][f], 0, 0, 0);
                o_acc[1][f] = __builtin_amdgcn_mfma_f32_16x16x32_bf16(pa1, vt, o_acc[1][f], 0, 0, 0);
            }
            __builtin_amdgcn_s_setprio(0);
        }

        // ---- stage next tile into the other buffer; ONE barrier ----
        if (kt < NT - 1) {
            const int nx = cur ^ 1;
            *(uint4*)&Ksh[nx][r_st * LDT + c0]     = pk0;
            *(uint4*)&Ksh[nx][r_st * LDT + c0 + 8] = pk1;
            *(uint4*)&Vts[nx][r_st * LDT + c0]     = pv0;
            *(uint4*)&Vts[nx][r_st * LDT + c0 + 8] = pv1;
            if (kt < NT - 2) {
                const int ok = (kt + 2) * 64 * DH;
                const int ov = (kt + 2) * 64;
                pk0 = *(const uint4*)(gKh + ok); pk1 = *(const uint4*)(gKh + ok + 8);
                pv0 = *(const uint4*)(gVt + ov); pv1 = *(const uint4*)(gVt + ov + 8);
            }
            __syncthreads();
            cur = nx;
        }
    }

    const int bb = bh >> 4, hh = bh & 15;
#pragma unroll
    for (int qb = 0; qb < 2; ++qb)
#pragma unroll
        for (int r = 0; r < 4; ++r) {
            const float inv = 1.f / l_acc[qb][r];
            const int row = q0 + w * 32 + qb * 16 + g * 4 + r;
#pragma unroll
            for (int f = 0; f < 4; ++f) {
                const float val = o_acc[qb][f][r] * inv;
                const size_t idx = ((size_t)(bb * S + row)) * D + hh * DH + f * 16 + l15;
                ushort hi, lo;
                split1(val, hi, lo);
                AOh[idx] = hi;
                AOl[idx] = lo;
            }
        }
}

extern "C" void kernel_launch(void* const* d_in, const int* in_sizes, int n_in,
                              void* d_out, int out_size, void* d_ws, size_t ws_size,
                              hipStream_t stream) {
    (void)in_sizes; (void)n_in; (void)out_size; (void)ws_size;
    const float* q  = (const float*)d_in[0];
    const float* k  = (const float*)d_in[1];
    const float* v  = (const float*)d_in[2];
    const float* Wq = (const float*)d_in[3];
    const float* Wk = (const float*)d_in[4];
    const float* Wv = (const float*)d_in[5];
    const float* Wo = (const float*)d_in[6];
    float* out = (float*)d_out;

    uint8_t* w8 = (uint8_t*)d_ws;
    constexpr size_t MB = 1u << 20;
    // weight splits: [0, 10 MB)
    ushort* Wqh = (ushort*)(w8 + 0 * MB);
    ushort* Wkh = (ushort*)(w8 + 2 * MB);
    ushort* Wvh = (ushort*)(w8 + 4 * MB);
    ushort* Woh = (ushort*)(w8 + 6 * MB);
    ushort* Wol = (ushort*)(w8 + 8 * MB);
    // projected bf16 tensors: [16, 40 MB)
    ushort* Qbh = (ushort*)(w8 + 16 * MB);
    ushort* Kbh = (ushort*)(w8 + 24 * MB);
    ushort* Vtb = (ushort*)(w8 + 32 * MB);
    // attention output hi/lo: [40, 56 MB)
    ushort* AOh = (ushort*)(w8 + 40 * MB);
    ushort* AOl = (ushort*)(w8 + 48 * MB);

    const int n4_w = (D * D) / 4;
    const dim3 blk(256);

    split_w<<<1024, blk, 0, stream>>>(
        (const float4*)Wq, (const float4*)Wk, (const float4*)Wv, (const float4*)Wo,
        (ushort4*)Wqh, (ushort4*)Wkh, (ushort4*)Wvh,
        (ushort4*)Woh, (ushort4*)Wol, n4_w);

    const float qscale = 0.125f * 1.4426950408889634f;
    gemm_qkv<<<dim3(N / 128, 24), blk, 0, stream>>>(
        q, k, v, Wqh, Wkh, Wvh, Qbh, Kbh, Vtb, qscale);

    attn_mfma<<<dim3(B * Hn, S / 128), blk, 0, stream>>>(
        Qbh, Kbh, Vtb, AOh, AOl);

    gemm_out<<<dim3(N / 128, D / 64), blk, 0, stream>>>(AOh, AOl, Woh, Wol, out);
}